// Round 2
// baseline (65.506 us; speedup 1.0000x reference)
//
#include <hip/hip_runtime.h>
#include <hip/hip_bf16.h>

// AlignConLoss: loss = sum_j [ log(sum_i exp(cn_i . an_j)) - cn_j . an_j ]
// (TEMPERATURE = 1; sim in [-1,1] so no LSE max-tracking needed)
// B = 8192, D = 256, inputs fp32, output: 1 fp32 scalar.

#define BROWS 8192
#define DIM   256

typedef __bf16 bf16x8 __attribute__((ext_vector_type(8)));
typedef float  f32x4  __attribute__((ext_vector_type(4)));

__device__ __forceinline__ void gload_lds16(const void* g, void* l) {
  // 16B/lane async global->LDS; LDS dest is wave-uniform base + lane*16.
  __builtin_amdgcn_global_load_lds(
      (const __attribute__((address_space(1))) unsigned int*)g,
      (__attribute__((address_space(3))) unsigned int*)l, 16, 0, 0);
}

// ---------------------------------------------------------------------------
// Kernel 1: per-row L2 norms. Writes bf16-normalized An (embedding1/anchor)
// and Cn (embedding2/contrast); exact fp32 diag[r] = (a_r . c_r)/(|a_r||c_r|).
// One wave per row (D=256 -> float4 per lane). Grid 2048 x 256.
// ---------------------------------------------------------------------------
__global__ __launch_bounds__(256) void prep_kernel(
    const float* __restrict__ E1, const float* __restrict__ E2,
    __hip_bfloat16* __restrict__ An, __hip_bfloat16* __restrict__ Cn,
    float* __restrict__ diag) {
  const int w    = threadIdx.x >> 6;
  const int lane = threadIdx.x & 63;
  const int row  = blockIdx.x * 4 + w;
  const size_t base = (size_t)row * DIM + lane * 4;

  const float4 a = *(const float4*)(E1 + base);
  const float4 c = *(const float4*)(E2 + base);

  float sa  = a.x*a.x + a.y*a.y + a.z*a.z + a.w*a.w;
  float sc  = c.x*c.x + c.y*c.y + c.z*c.z + c.w*c.w;
  float sac = a.x*c.x + a.y*c.y + a.z*c.z + a.w*c.w;
#pragma unroll
  for (int o = 32; o > 0; o >>= 1) {
    sa  += __shfl_down(sa,  o);
    sc  += __shfl_down(sc,  o);
    sac += __shfl_down(sac, o);
  }
  const float inva = 1.0f / fmaxf(sqrtf(__shfl(sa, 0)), 1e-8f);
  const float invc = 1.0f / fmaxf(sqrtf(__shfl(sc, 0)), 1e-8f);

  An[base + 0] = __float2bfloat16(a.x * inva);
  An[base + 1] = __float2bfloat16(a.y * inva);
  An[base + 2] = __float2bfloat16(a.z * inva);
  An[base + 3] = __float2bfloat16(a.w * inva);
  Cn[base + 0] = __float2bfloat16(c.x * invc);
  Cn[base + 1] = __float2bfloat16(c.y * invc);
  Cn[base + 2] = __float2bfloat16(c.z * invc);
  Cn[base + 3] = __float2bfloat16(c.w * invc);
  if (lane == 0) diag[row] = sac * inva * invc;
}

// ---------------------------------------------------------------------------
// Kernel 2: 128x128 sim tile via mfma_f32_16x16x32_bf16 (NT gemm: both
// operands row-major [rows][K]); epilogue: exp + per-column reduce, one
// atomicAdd per column per block into colsum[8192].
// Staging: global_load_lds width 16, linear LDS [128][64] bf16 per matrix;
// bank-conflict fix per guide rule #21: inverse-XOR-swizzled GLOBAL source
// (slot_phys holds k-block slot_phys ^ (row&7)) + same XOR on ds_read.
// ---------------------------------------------------------------------------
__global__ __launch_bounds__(256) void gemm_colsum_kernel(
    const __hip_bfloat16* __restrict__ Cn,   // contrast rows -> sim rows i
    const __hip_bfloat16* __restrict__ An,   // anchor rows   -> sim cols j
    float* __restrict__ colsum) {
  __shared__ __align__(16) char ldsC[16384];   // [128 rows][64 k] bf16
  __shared__ __align__(16) char ldsA[16384];
  __shared__ float ldscol[2][128];

  const int tid  = threadIdx.x;
  const int lane = tid & 63;
  const int w    = tid >> 6;      // 4 waves
  const int wr   = w >> 1;        // wave row (i) 0..1  -> 64 rows each
  const int wc   = w & 1;         // wave col (j) 0..1  -> 64 cols each

  const int jtile = blockIdx.x & 63;   // consecutive blocks share itile (L2)
  const int itile = blockIdx.x >> 6;
  const int i0 = itile * 128;
  const int j0 = jtile * 128;

  // staging geometry: call s covers rows s*32..s*32+31; thread -> (row, slot)
  const int rl  = tid >> 3;               // row within 32-row chunk
  const int kbl = (tid & 7) ^ (rl & 7);   // inverse-swizzled logical k-block
  const __hip_bfloat16* gC = Cn + (size_t)(i0 + rl) * DIM + kbl * 8;
  const __hip_bfloat16* gA = An + (size_t)(j0 + rl) * DIM + kbl * 8;
  char* lbC = ldsC + w * 1024;            // wave-uniform LDS base
  char* lbA = ldsA + w * 1024;

  f32x4 acc[4][4] = {};

#pragma unroll
  for (int ks = 0; ks < 4; ++ks) {        // K = 256 = 4 * BK(64)
    __syncthreads();                      // LDS reuse guard
    const int gk = ks * 64;
#pragma unroll
    for (int s = 0; s < 4; ++s) {
      gload_lds16(gC + (size_t)s * 32 * DIM + gk, lbC + s * 4096);
      gload_lds16(gA + (size_t)s * 32 * DIM + gk, lbA + s * 4096);
    }
    __syncthreads();                      // drains vmcnt before ds_read

    const int q  = lane >> 4;
    const int sw = lane & 7;
#pragma unroll
    for (int kk = 0; kk < 2; ++kk) {      // two K=32 MFMA chunks per BK
      bf16x8 af[4], bfv[4];
      const int slot = (q + kk * 4) ^ sw; // undo source swizzle (r&7==lane&7)
#pragma unroll
      for (int m = 0; m < 4; ++m) {
        const int r = wr * 64 + m * 16 + (lane & 15);
        af[m] = *(const bf16x8*)(ldsC + r * 128 + slot * 16);
      }
#pragma unroll
      for (int n = 0; n < 4; ++n) {
        const int r = wc * 64 + n * 16 + (lane & 15);
        bfv[n] = *(const bf16x8*)(ldsA + r * 128 + slot * 16);
      }
#pragma unroll
      for (int m = 0; m < 4; ++m)
#pragma unroll
        for (int n = 0; n < 4; ++n)
          acc[m][n] = __builtin_amdgcn_mfma_f32_16x16x32_bf16(
              af[m], bfv[n], acc[m][n], 0, 0, 0);
    }
  }

  // Epilogue: colpart[j] = sum over this block's 128 i-rows of exp(sim).
  // C/D layout (m89-verified): col = lane&15, row = (lane>>4)*4 + reg.
#pragma unroll
  for (int n = 0; n < 4; ++n) {
    float s = 0.f;
#pragma unroll
    for (int m = 0; m < 4; ++m) {
      const f32x4 v = acc[m][n];
      s += __expf(v[0]) + __expf(v[1]) + __expf(v[2]) + __expf(v[3]);
    }
    s += __shfl_xor(s, 16);   // combine the 4 row-groups sharing lane&15
    s += __shfl_xor(s, 32);
    if (lane < 16) ldscol[wr][wc * 64 + n * 16 + lane] = s;
  }
  __syncthreads();
  if (tid < 128) {
    const float v = ldscol[0][tid] + ldscol[1][tid];
    atomicAdd(&colsum[j0 + tid], v);
  }
}

// ---------------------------------------------------------------------------
// Kernel 3: loss = sum_j log(colsum[j]) - diag[j].  Single block.
// ---------------------------------------------------------------------------
__global__ __launch_bounds__(256) void finalize_kernel(
    const float* __restrict__ colsum, const float* __restrict__ diag,
    float* __restrict__ out) {
  const int t = threadIdx.x;
  float s = 0.f;
  for (int j = t; j < BROWS; j += 256) s += logf(colsum[j]) - diag[j];
#pragma unroll
  for (int o = 32; o > 0; o >>= 1) s += __shfl_down(s, o);
  __shared__ float red[4];
  if ((t & 63) == 0) red[t >> 6] = s;
  __syncthreads();
  if (t == 0) out[0] = red[0] + red[1] + red[2] + red[3];
}

// ---------------------------------------------------------------------------
// ws layout (needs ~8.07 MB):
//   [0, 4MiB)          Cn bf16 [8192*256]
//   [4MiB, 8MiB)       An bf16 [8192*256]
//   [8MiB, +32KiB)     colsum f32 [8192]
//   [8MiB+32K, +32KiB) diag   f32 [8192]
// ---------------------------------------------------------------------------
extern "C" void kernel_launch(void* const* d_in, const int* in_sizes, int n_in,
                              void* d_out, int out_size, void* d_ws, size_t ws_size,
                              hipStream_t stream) {
  const float* E1 = (const float*)d_in[0];   // encoder_embedding1 -> anchors
  const float* E2 = (const float*)d_in[1];   // encoder_embedding2 -> contrast
  char* ws = (char*)d_ws;
  __hip_bfloat16* Cn = (__hip_bfloat16*)(ws);
  __hip_bfloat16* An = (__hip_bfloat16*)(ws + (size_t)4 * 1024 * 1024);
  float* colsum = (float*)(ws + (size_t)8 * 1024 * 1024);
  float* diag   = (float*)(ws + (size_t)8 * 1024 * 1024 + 32 * 1024);
  float* out = (float*)d_out;

  hipMemsetAsync(colsum, 0, BROWS * sizeof(float), stream);
  prep_kernel<<<BROWS / 4, 256, 0, stream>>>(E1, E2, An, Cn, diag);
  gemm_colsum_kernel<<<(BROWS / 128) * (BROWS / 128), 256, 0, stream>>>(Cn, An, colsum);
  finalize_kernel<<<1, 256, 0, stream>>>(colsum, diag, out);
}

// Round 6
// 59.718 us; speedup vs baseline: 1.0969x; 1.0969x over previous
//
#include <hip/hip_runtime.h>
#include <hip/hip_bf16.h>

// AlignConLoss: loss = sum_j [ log(sum_i exp(cn_i . an_j)) - cn_j . an_j ]
// (TEMPERATURE = 1; sim in [-1,1] so no LSE max-tracking needed)
// B = 8192, D = 256, inputs fp32, output: 1 fp32 scalar.
//
// R2 -> R3: removed hipMemsetAsync(colsum) — the runtime's 32KB
// fillBufferAligned dispatch cost ~43us/replay (top dispatch in profile).
// colsum is now zeroed by prep_kernel (blocks 0..31), which runs before
// gemm_colsum on the same stream.

#define BROWS 8192
#define DIM   256

typedef __bf16 bf16x8 __attribute__((ext_vector_type(8)));
typedef float  f32x4  __attribute__((ext_vector_type(4)));

__device__ __forceinline__ void gload_lds16(const void* g, void* l) {
  // 16B/lane async global->LDS; LDS dest is wave-uniform base + lane*16.
  __builtin_amdgcn_global_load_lds(
      (const __attribute__((address_space(1))) unsigned int*)g,
      (__attribute__((address_space(3))) unsigned int*)l, 16, 0, 0);
}

// ---------------------------------------------------------------------------
// Kernel 1: per-row L2 norms. Writes bf16-normalized An (embedding1/anchor)
// and Cn (embedding2/contrast); exact fp32 diag[r] = (a_r . c_r)/(|a_r||c_r|).
// One wave per row (D=256 -> float4 per lane). Also zeroes colsum[8192]
// (blocks 0..31) so no runtime memset is needed.
// ---------------------------------------------------------------------------
__global__ __launch_bounds__(256) void prep_kernel(
    const float* __restrict__ E1, const float* __restrict__ E2,
    __hip_bfloat16* __restrict__ An, __hip_bfloat16* __restrict__ Cn,
    float* __restrict__ diag, float* __restrict__ colsum) {
  if (blockIdx.x < 32) {
    colsum[blockIdx.x * 256 + threadIdx.x] = 0.f;
  }

  const int w    = threadIdx.x >> 6;
  const int lane = threadIdx.x & 63;
  const int row  = blockIdx.x * 4 + w;
  const size_t base = (size_t)row * DIM + lane * 4;

  const float4 a = *(const float4*)(E1 + base);
  const float4 c = *(const float4*)(E2 + base);

  float sa  = a.x*a.x + a.y*a.y + a.z*a.z + a.w*a.w;
  float sc  = c.x*c.x + c.y*c.y + c.z*c.z + c.w*c.w;
  float sac = a.x*c.x + a.y*c.y + a.z*c.z + a.w*c.w;
#pragma unroll
  for (int o = 32; o > 0; o >>= 1) {
    sa  += __shfl_down(sa,  o);
    sc  += __shfl_down(sc,  o);
    sac += __shfl_down(sac, o);
  }
  const float inva = 1.0f / fmaxf(sqrtf(__shfl(sa, 0)), 1e-8f);
  const float invc = 1.0f / fmaxf(sqrtf(__shfl(sc, 0)), 1e-8f);

  An[base + 0] = __float2bfloat16(a.x * inva);
  An[base + 1] = __float2bfloat16(a.y * inva);
  An[base + 2] = __float2bfloat16(a.z * inva);
  An[base + 3] = __float2bfloat16(a.w * inva);
  Cn[base + 0] = __float2bfloat16(c.x * invc);
  Cn[base + 1] = __float2bfloat16(c.y * invc);
  Cn[base + 2] = __float2bfloat16(c.z * invc);
  Cn[base + 3] = __float2bfloat16(c.w * invc);
  if (lane == 0) diag[row] = sac * inva * invc;
}

// ---------------------------------------------------------------------------
// Kernel 2: 128x128 sim tile via mfma_f32_16x16x32_bf16 (NT gemm: both
// operands row-major [rows][K]); epilogue: exp + per-column reduce, one
// atomicAdd per column per block into colsum[8192].
// Staging: global_load_lds width 16, linear LDS [128][64] bf16 per matrix;
// bank-conflict fix per guide rule #21: inverse-XOR-swizzled GLOBAL source
// (slot_phys holds k-block slot_phys ^ (row&7)) + same XOR on ds_read.
// ---------------------------------------------------------------------------
__global__ __launch_bounds__(256) void gemm_colsum_kernel(
    const __hip_bfloat16* __restrict__ Cn,   // contrast rows -> sim rows i
    const __hip_bfloat16* __restrict__ An,   // anchor rows   -> sim cols j
    float* __restrict__ colsum) {
  __shared__ __align__(16) char ldsC[16384];   // [128 rows][64 k] bf16
  __shared__ __align__(16) char ldsA[16384];
  __shared__ float ldscol[2][128];

  const int tid  = threadIdx.x;
  const int lane = tid & 63;
  const int w    = tid >> 6;      // 4 waves
  const int wr   = w >> 1;        // wave row (i) 0..1  -> 64 rows each
  const int wc   = w & 1;         // wave col (j) 0..1  -> 64 cols each

  const int jtile = blockIdx.x & 63;   // consecutive blocks share itile (L2)
  const int itile = blockIdx.x >> 6;
  const int i0 = itile * 128;
  const int j0 = jtile * 128;

  // staging geometry: call s covers rows s*32..s*32+31; thread -> (row, slot)
  const int rl  = tid >> 3;               // row within 32-row chunk
  const int kbl = (tid & 7) ^ (rl & 7);   // inverse-swizzled logical k-block
  const __hip_bfloat16* gC = Cn + (size_t)(i0 + rl) * DIM + kbl * 8;
  const __hip_bfloat16* gA = An + (size_t)(j0 + rl) * DIM + kbl * 8;
  char* lbC = ldsC + w * 1024;            // wave-uniform LDS base
  char* lbA = ldsA + w * 1024;

  f32x4 acc[4][4] = {};

#pragma unroll
  for (int ks = 0; ks < 4; ++ks) {        // K = 256 = 4 * BK(64)
    __syncthreads();                      // LDS reuse guard
    const int gk = ks * 64;
#pragma unroll
    for (int s = 0; s < 4; ++s) {
      gload_lds16(gC + (size_t)s * 32 * DIM + gk, lbC + s * 4096);
      gload_lds16(gA + (size_t)s * 32 * DIM + gk, lbA + s * 4096);
    }
    __syncthreads();                      // drains vmcnt before ds_read

    const int q  = lane >> 4;
    const int sw = lane & 7;
#pragma unroll
    for (int kk = 0; kk < 2; ++kk) {      // two K=32 MFMA chunks per BK
      bf16x8 af[4], bfv[4];
      const int slot = (q + kk * 4) ^ sw; // undo source swizzle (r&7==lane&7)
#pragma unroll
      for (int m = 0; m < 4; ++m) {
        const int r = wr * 64 + m * 16 + (lane & 15);
        af[m] = *(const bf16x8*)(ldsC + r * 128 + slot * 16);
      }
#pragma unroll
      for (int n = 0; n < 4; ++n) {
        const int r = wc * 64 + n * 16 + (lane & 15);
        bfv[n] = *(const bf16x8*)(ldsA + r * 128 + slot * 16);
      }
#pragma unroll
      for (int m = 0; m < 4; ++m)
#pragma unroll
        for (int n = 0; n < 4; ++n)
          acc[m][n] = __builtin_amdgcn_mfma_f32_16x16x32_bf16(
              af[m], bfv[n], acc[m][n], 0, 0, 0);
    }
  }

  // Epilogue: colpart[j] = sum over this block's 128 i-rows of exp(sim).
  // C/D layout (m89-verified): col = lane&15, row = (lane>>4)*4 + reg.
#pragma unroll
  for (int n = 0; n < 4; ++n) {
    float s = 0.f;
#pragma unroll
    for (int m = 0; m < 4; ++m) {
      const f32x4 v = acc[m][n];
      s += __expf(v[0]) + __expf(v[1]) + __expf(v[2]) + __expf(v[3]);
    }
    s += __shfl_xor(s, 16);   // combine the 4 row-groups sharing lane&15
    s += __shfl_xor(s, 32);
    if (lane < 16) ldscol[wr][wc * 64 + n * 16 + lane] = s;
  }
  __syncthreads();
  if (tid < 128) {
    const float v = ldscol[0][tid] + ldscol[1][tid];
    atomicAdd(&colsum[j0 + tid], v);
  }
}

// ---------------------------------------------------------------------------
// Kernel 3: loss = sum_j log(colsum[j]) - diag[j].  Single block.
// ---------------------------------------------------------------------------
__global__ __launch_bounds__(256) void finalize_kernel(
    const float* __restrict__ colsum, const float* __restrict__ diag,
    float* __restrict__ out) {
  const int t = threadIdx.x;
  float s = 0.f;
  for (int j = t; j < BROWS; j += 256) s += logf(colsum[j]) - diag[j];
#pragma unroll
  for (int o = 32; o > 0; o >>= 1) s += __shfl_down(s, o);
  __shared__ float red[4];
  if ((t & 63) == 0) red[t >> 6] = s;
  __syncthreads();
  if (t == 0) out[0] = red[0] + red[1] + red[2] + red[3];
}

// ---------------------------------------------------------------------------
// ws layout (needs ~8.07 MB):
//   [0, 4MiB)          Cn bf16 [8192*256]
//   [4MiB, 8MiB)       An bf16 [8192*256]
//   [8MiB, +32KiB)     colsum f32 [8192]
//   [8MiB+32K, +32KiB) diag   f32 [8192]
// ---------------------------------------------------------------------------
extern "C" void kernel_launch(void* const* d_in, const int* in_sizes, int n_in,
                              void* d_out, int out_size, void* d_ws, size_t ws_size,
                              hipStream_t stream) {
  const float* E1 = (const float*)d_in[0];   // encoder_embedding1 -> anchors
  const float* E2 = (const float*)d_in[1];   // encoder_embedding2 -> contrast
  char* ws = (char*)d_ws;
  __hip_bfloat16* Cn = (__hip_bfloat16*)(ws);
  __hip_bfloat16* An = (__hip_bfloat16*)(ws + (size_t)4 * 1024 * 1024);
  float* colsum = (float*)(ws + (size_t)8 * 1024 * 1024);
  float* diag   = (float*)(ws + (size_t)8 * 1024 * 1024 + 32 * 1024);
  float* out = (float*)d_out;

  prep_kernel<<<BROWS / 4, 256, 0, stream>>>(E1, E2, An, Cn, diag, colsum);
  gemm_colsum_kernel<<<(BROWS / 128) * (BROWS / 128), 256, 0, stream>>>(Cn, An, colsum);
  finalize_kernel<<<1, 256, 0, stream>>>(colsum, diag, out);
}